// Round 16
// baseline (5586.470 us; speedup 1.0000x reference)
//
#include <hip/hip_runtime.h>
#include <stdint.h>

typedef unsigned short u16;

#define T_STEPS 512
#define BATCH   64
#define DIN     512
#define HID     1024
#define G4      4096
#define NBLK    128
#define NH      8       // hidden units per block
#define NC      32      // gate columns per block (4*NH)
#define THREADS 512

#define U_LD    1032    // 1024 + 8 pad
#define W_LD    520     // 512 + 8 pad (init staging only)

// LDS: Ut[NC*U_LD] @0 PERSISTENT (66048B);
//      Wt stage @66048 (init, 33280B) aliased by run-phase zp f32[4][64][33] (33792B)
#define SM_BYTES 99840
#define WT_OFF   66048

// ws map
#define XB_BYTES ((size_t)T_STEPS * BATCH * DIN * 2)   // 32 MB bf16 x
#define HB_OFF   XB_BYTES        // tagged h u32 [par2][kblk128][row64][u8]
#define HB_PAR   262144
#define HB_BYTES (2u * HB_PAR)   // 512 KB
#define WS_NEED  (HB_OFF + HB_BYTES)

typedef float f32x16 __attribute__((ext_vector_type(16)));
typedef short bf16x8 __attribute__((ext_vector_type(8)));
typedef unsigned uint32x4 __attribute__((ext_vector_type(4)));

__device__ __forceinline__ u16 f2bf(float f) {
  unsigned u = __float_as_uint(f);
  u += 0x7fffu + ((u >> 16) & 1u);   // RNE
  return (u16)(u >> 16);
}
__device__ __forceinline__ float sigm(float x) {
  return __builtin_amdgcn_rcpf(1.f + __expf(-x));
}
__device__ __forceinline__ float fast_tanh(float x) {
  return 1.f - 2.f * __builtin_amdgcn_rcpf(__expf(2.f * x) + 1.f);
}

// sc0 sc1 = coherence-point access; flat 64b VGPR address (all VMEM as asm so
// vmcnt counts are exact).
__device__ __forceinline__ uint32x4 load16_sc(uint64_t addr) {
  uint32x4 d;
  asm volatile("global_load_dwordx4 %0, %1, off sc0 sc1" : "=v"(d) : "v"(addr));
  return d;
}
__device__ __forceinline__ uint32x4 load16_plain(uint64_t addr) {
  uint32x4 d;
  asm volatile("global_load_dwordx4 %0, %1, off" : "=v"(d) : "v"(addr));
  return d;
}
__device__ __forceinline__ void store16_sc(uint64_t addr, uint32x4 v) {
  asm volatile("global_store_dwordx4 %0, %1, off sc0 sc1" :: "v"(addr), "v"(v) : "memory");
}
#define WAITV(n) asm volatile("s_waitcnt vmcnt(" #n ")" ::: "memory")
#define SBAR()   __builtin_amdgcn_sched_barrier(0)

// x[B][T][D] fp32 -> xb[T][B][D] bf16
__global__ void cvt_x(const float* __restrict__ x, u16* __restrict__ xb) {
  int i = blockIdx.x * 256 + threadIdx.x;
  int dblk = i & 63;
  int rest = i >> 6;
  int b = rest & 63;
  int t = rest >> 6;
  const float4* s = reinterpret_cast<const float4*>(x + ((size_t)(b * T_STEPS + t)) * DIN + dblk * 8);
  float4 f0 = s[0], f1 = s[1];
  uint4 o;
  o.x = (unsigned)f2bf(f0.x) | ((unsigned)f2bf(f0.y) << 16);
  o.y = (unsigned)f2bf(f0.z) | ((unsigned)f2bf(f0.w) << 16);
  o.z = (unsigned)f2bf(f1.x) | ((unsigned)f2bf(f1.y) << 16);
  o.w = (unsigned)f2bf(f1.z) | ((unsigned)f2bf(f1.w) << 16);
  *reinterpret_cast<uint4*>(xb + ((size_t)(t * BATCH + b)) * DIN + dblk * 8) = o;
}

// Persistent LSTM, TAGGED-h protocol: h word u32 = bf16(h)<<16 | step.
// One coherence-point RT per step: consume = 32 speculative b128 loads +
// in-register tag check (+bounded retry); publish = fire-and-forget shfl-packed
// 16B stores (dword-atomic => self-certifying). NO flags, NO acks.
// ABA-safe: a tag-(t+2) write needs its producer past step t+1, which needs
// OUR h(t+1) -- unpublished while we're stuck at t.
// GEMM: r14-validated 32x32x16, 8 waves = 2 M-tiles x 4 K-splits; U-frags
// read per-step from persistent LDS (frees 64 VGPRs for the 32-deep h flight).
__launch_bounds__(THREADS)
__global__ void lstm_kernel(const float* __restrict__ W, const float* __restrict__ U,
                            const float* __restrict__ bias, const u16* __restrict__ xb,
                            char* __restrict__ ws, float* __restrict__ out) {
  __shared__ __align__(16) char smraw[SM_BYTES];
  u16* Ut = (u16*)smraw;                  // PERSISTENT
  u16* Wt = (u16*)(smraw + WT_OFF);       // init staging only
  float* zp = (float*)(smraw + WT_OFF);   // run phase: [4][64][33]

  const int tid = threadIdx.x;
  const int bid = blockIdx.x;
  const int j0 = bid * NH;

  // ---- init: stage transposed bf16 weight slices ----
  for (int idx = tid; idx < NC * HID; idx += THREADS) {
    int c = idx & (NC - 1);
    int k = idx >> 5;
    int gcol = ((c >> 3) << 10) + j0 + (c & 7);
    Ut[c * U_LD + k] = f2bf(U[(size_t)k * G4 + gcol]);
  }
  for (int idx = tid; idx < NC * DIN; idx += THREADS) {
    int c = idx & (NC - 1);
    int k = idx >> 5;
    int gcol = ((c >> 3) << 10) + j0 + (c & 7);
    Wt[c * W_LD + k] = f2bf(W[(size_t)k * G4 + gcol]);
  }
  __syncthreads();

  const int l   = tid & 63;
  const int wv  = tid >> 6;
  const int m_t = wv & 1;          // batch rows m_t*32 .. +31
  const int ks  = wv >> 1;         // K-split 0..3
  const int cl  = l & 31;
  const int q   = l >> 5;

  // ---- W fragments -> registers (32 VGPR); U stays in LDS ----
  bf16x8 wbf[8];
  {
    const u16* wb = Wt + cl * W_LD + ks * 128 + q * 8;
#pragma unroll
    for (int s = 0; s < 8; ++s) wbf[s] = *(const bf16x8*)(wb + s * 16);
  }
  __syncthreads();   // Wt dead; zp live from here (Ut persists)

  const u16* ubp = Ut + cl * U_LD + ks * 256 + q * 8;  // per-step LDS B-frags

  const int row = m_t * 32 + cl;   // batch row this lane loads for A
  const int pb = tid >> 3;         // gates: row
  const int pu = tid & 7;          // gates: unit
  float c_reg = 0.f;
  const float bi  = bias[j0 + pu];
  const float bf_ = bias[1024 + j0 + pu];
  const float bg  = bias[2048 + j0 + pu];
  const float bo  = bias[3072 + j0 + pu];

  const uint64_t hbB = (uint64_t)ws + HB_OFF;
  const uint64_t xb64 = (uint64_t)xb;
  // consumer: frag s covers kblk = ks*32 + 2s + q; byte = kblk*2048 + row*32
  const uint64_t hoff = (uint64_t)(ks * 32 + q) * 2048 + (uint64_t)row * 32;
  // publisher: leader (l&3)==0 stores 16B = 4 units of row tid>>3
  const uint64_t puboff = (uint64_t)bid * 2048 + (uint64_t)(tid >> 3) * 32 +
                          (uint64_t)((l >> 2) & 1) * 16;

  int alive = 1;

  for (int t = 0; t < T_STEPS; ++t) {
    const unsigned tagv = (unsigned)t;
    const uint64_t hb = hbB + (uint64_t)(t & 1) * HB_PAR + hoff;

    // ---- issue 32 tagged-h loads (sc1) + 8 x loads (plain) ----
    uint32x4 hbuf[32];
#define ISSUEH() do { _Pragma("unroll") for (int s_ = 0; s_ < 16; ++s_) { \
      hbuf[2 * s_]     = load16_sc(hb + (uint64_t)s_ * 4096); \
      hbuf[2 * s_ + 1] = load16_sc(hb + (uint64_t)s_ * 4096 + 16); } } while (0)
    ISSUEH();
    uint32x4 xr[8];
    {
      const uint64_t xa = xb64 + ((uint64_t)t * (BATCH * DIN) +
                                  (uint64_t)row * DIN + ks * 128 + q * 8) * 2;
#pragma unroll
      for (int s = 0; s < 8; ++s) xr[s] = load16_plain(xa + (uint64_t)s * 32);
    }

    // ---- single-RT consume: drain (also acks prev publish), tag-check, retry ----
    int spins = 0;
    while (alive) {
      WAITV(0); SBAR();
      unsigned bad = 0;
#pragma unroll
      for (int s = 0; s < 32; ++s) {
#pragma unroll
        for (int e = 0; e < 4; ++e) bad |= (hbuf[s][e] ^ tagv) & 0xffffu;
      }
      if (__all(bad == 0)) break;
      if (++spins > (1 << 18)) { alive = 0; break; }   // loud garbage, no hang
      __builtin_amdgcn_s_sleep(4);
      ISSUEH();
    }
#undef ISSUEH

    // ---- h_t @ U (unpack pairs -> bf16x8; U frags from persistent LDS) ----
    f32x16 acc = {0.f,0.f,0.f,0.f,0.f,0.f,0.f,0.f,0.f,0.f,0.f,0.f,0.f,0.f,0.f,0.f};
#pragma unroll
    for (int s = 0; s < 16; ++s) {
      uint32x4 d0 = hbuf[2 * s], d1 = hbuf[2 * s + 1];
      uint32x4 pk;
      pk[0] = (d0[0] >> 16) | (d0[1] & 0xffff0000u);
      pk[1] = (d0[2] >> 16) | (d0[3] & 0xffff0000u);
      pk[2] = (d1[0] >> 16) | (d1[1] & 0xffff0000u);
      pk[3] = (d1[2] >> 16) | (d1[3] & 0xffff0000u);
      bf16x8 a = __builtin_bit_cast(bf16x8, pk);
      bf16x8 uf = *(const bf16x8*)(ubp + s * 16);
      acc = __builtin_amdgcn_mfma_f32_32x32x16_bf16(a, uf, acc, 0, 0, 0);
    }
    // ---- x_t @ W ----
#pragma unroll
    for (int s = 0; s < 8; ++s)
      acc = __builtin_amdgcn_mfma_f32_32x32x16_bf16(
          __builtin_bit_cast(bf16x8, xr[s]), wbf[s], acc, 0, 0, 0);

    // ---- K-split partial -> LDS (C layout: col=cl, row=(r&3)+8*(r>>2)+4*q) ----
#pragma unroll
    for (int r = 0; r < 16; ++r) {
      int rl = (r & 3) + 8 * (r >> 2) + 4 * q;
      zp[ks * 2112 + (m_t * 32 + rl) * 33 + cl] = acc[r];
    }
    __syncthreads();   // b1: zp write -> read

    // ---- reduce partials + gates: one thread per (row, unit) ----
    float zi = bi, zf = bf_, zg = bg, zo = bo;
#pragma unroll
    for (int k2 = 0; k2 < 4; ++k2) {
      const float* zr = zp + k2 * 2112 + pb * 33;
      zi += zr[pu]; zf += zr[pu + 8]; zg += zr[pu + 16]; zo += zr[pu + 24];
    }
    float ig = sigm(zi), fg = sigm(zf), og = sigm(zo);
    float gg = fast_tanh(zg);
    c_reg = fg * c_reg + ig * gg;
    float h = og * fast_tanh(c_reg);

    // ---- tagged publish: pack 4 lanes' u32 -> 16B on leaders; fire-and-forget ----
    unsigned hval = ((unsigned)f2bf(h) << 16) | (unsigned)(t + 1);
    int base_ = l & ~3;
    uint32x4 hv;
    hv[0] = __shfl(hval, base_);
    hv[1] = __shfl(hval, base_ + 1);
    hv[2] = __shfl(hval, base_ + 2);
    hv[3] = __shfl(hval, base_ + 3);
    if ((l & 3) == 0)
      store16_sc(hbB + (uint64_t)((t + 1) & 1) * HB_PAR + puboff, hv);

    if (t == T_STEPS - 1) {
      float* orow = out + (size_t)pb * 3072 + j0 + pu;
      orow[0]    = h;       // h_T
      orow[1024] = h;       // h_T again
      orow[2048] = c_reg;   // c_T
    }
    __syncthreads();   // b2: zp reads done before next step's writes
  }
}

extern "C" void kernel_launch(void* const* d_in, const int* in_sizes, int n_in,
                              void* d_out, int out_size, void* d_ws, size_t ws_size,
                              hipStream_t stream) {
  const float* x = (const float*)d_in[0];
  const float* W = (const float*)d_in[1];
  const float* U = (const float*)d_in[2];
  const float* b = (const float*)d_in[3];
  float* out = (float*)d_out;

  if (ws_size < WS_NEED) return;  // loud failure: output stays poisoned

  u16* xb = (u16*)d_ws;
  // zero tagged-h buffers (tag 0 == valid h_0 = 0) — replayed every launch
  hipMemsetAsync((char*)d_ws + HB_OFF, 0, HB_BYTES, stream);
  cvt_x<<<(T_STEPS * BATCH * DIN / 8 + 255) / 256, 256, 0, stream>>>(x, xb);
  lstm_kernel<<<NBLK, THREADS, 0, stream>>>(W, U, b, xb, (char*)d_ws, out);
}

// Round 17
// 3338.120 us; speedup vs baseline: 1.6735x; 1.6735x over previous
//
#include <hip/hip_runtime.h>
#include <stdint.h>

typedef unsigned short u16;

#define T_STEPS 512
#define BATCH   64
#define DIN     512
#define HID     1024
#define G4      4096
#define NBLK    128
#define NH      8       // hidden units per block; block bid owns kblk=bid
#define NC      32      // gate cols per block; col c = u_local*4 + gate
#define THREADS 512

#define U_LD    1032    // 1024 + 8 pad (init staging only)
#define W_LD    520     // 512 + 8 pad  (init staging only)

// LDS: init  Ut[NC*U_LD] @0 (66048B), Wt[NC*W_LD] @66048 (33280B)
//      run   zp f32[8][32][36] @0 (36864B, aliases dead Ut)
#define SM_BYTES 99328
#define WT_OFF   66048

// ws map
#define XB_BYTES ((size_t)T_STEPS * BATCH * DIN * 2)   // 32 MB bf16 x
#define HB_OFF   XB_BYTES   // tagged h u32: [ch2][par2][kblk128][row32][u8]
#define HB_PAR   131072     // one parity buffer = 128*32*8*4
#define HB_CH    (2 * HB_PAR)
#define HB_BYTES (2u * HB_CH)                          // 512 KB
#define WS_NEED  (HB_OFF + HB_BYTES)

typedef float f32x16 __attribute__((ext_vector_type(16)));
typedef short bf16x8 __attribute__((ext_vector_type(8)));
typedef unsigned uint32x4 __attribute__((ext_vector_type(4)));

__device__ __forceinline__ u16 f2bf(float f) {
  unsigned u = __float_as_uint(f);
  u += 0x7fffu + ((u >> 16) & 1u);   // RNE
  return (u16)(u >> 16);
}
__device__ __forceinline__ float sigm(float x) {
  return __builtin_amdgcn_rcpf(1.f + __expf(-x));
}
__device__ __forceinline__ float fast_tanh(float x) {
  return 1.f - 2.f * __builtin_amdgcn_rcpf(__expf(2.f * x) + 1.f);
}

// sc0 sc1 = coherence-point access (bypass L1/L2); flat 64b VGPR address.
__device__ __forceinline__ uint32x4 load16_sc(uint64_t addr) {
  uint32x4 d;
  asm volatile("global_load_dwordx4 %0, %1, off sc0 sc1" : "=v"(d) : "v"(addr));
  return d;
}
__device__ __forceinline__ uint32x4 load16_plain(uint64_t addr) {
  uint32x4 d;
  asm volatile("global_load_dwordx4 %0, %1, off" : "=v"(d) : "v"(addr));
  return d;
}
__device__ __forceinline__ void store16_sc(uint64_t addr, uint32x4 v) {
  asm volatile("global_store_dwordx4 %0, %1, off sc0 sc1" :: "v"(addr), "v"(v) : "memory");
}
#define WAITV(n) asm volatile("s_waitcnt vmcnt(" #n ")" ::: "memory")
#define SBAR()   __builtin_amdgcn_sched_barrier(0)

// x[B][T][D] fp32 -> xb[T][B][D] bf16
__global__ void cvt_x(const float* __restrict__ x, u16* __restrict__ xb) {
  int i = blockIdx.x * 256 + threadIdx.x;
  int dblk = i & 63;
  int rest = i >> 6;
  int b = rest & 63;
  int t = rest >> 6;
  const float4* s = reinterpret_cast<const float4*>(x + ((size_t)(b * T_STEPS + t)) * DIN + dblk * 8);
  float4 f0 = s[0], f1 = s[1];
  uint4 o;
  o.x = (unsigned)f2bf(f0.x) | ((unsigned)f2bf(f0.y) << 16);
  o.y = (unsigned)f2bf(f0.z) | ((unsigned)f2bf(f0.w) << 16);
  o.z = (unsigned)f2bf(f1.x) | ((unsigned)f2bf(f1.y) << 16);
  o.w = (unsigned)f2bf(f1.z) | ((unsigned)f2bf(f1.w) << 16);
  *reinterpret_cast<uint4*>(xb + ((size_t)(t * BATCH + b)) * DIN + dblk * 8) = o;
}

// Dual-chain persistent LSTM with TAGGED h (u32 = bf16(h)<<16 | step).
// NO flags, NO acks: each h dword self-certifies (dword atomicity), so the
// publish->consume chain is ONE coherence-point RT. Chains = batch halves,
// alternating phases. Per phase: 8 waves = 8 exclusive K-splits (128 HID +
// 64 DIN each), M=32; h = 16 b128/lane (64 VGPR, single buffer reused);
// next phase's bundle issued MID-phase -> serviced well after the
// publish (1.5us margin) -> tag passes first try; bounded retry for skew.
// ABA-safe: my tag-pass of h(CH,T) needed every block's publish of step T,
// which happens after that block drained its reads of h(CH,T-1) (same parity
// I overwrite) at its prior-phase start.
__launch_bounds__(THREADS, 2)
__global__ void lstm_kernel(const float* __restrict__ W, const float* __restrict__ U,
                            const float* __restrict__ bias, const u16* __restrict__ xb,
                            char* __restrict__ ws, float* __restrict__ out) {
  __shared__ __align__(16) char smraw[SM_BYTES];
  u16* Ut = (u16*)smraw;
  u16* Wt = (u16*)(smraw + WT_OFF);
  float (*zp)[32][36] = (float(*)[32][36])smraw;   // run phase (Ut dead)

  const int tid = threadIdx.x;
  const int bid = blockIdx.x;
  const int j0 = bid * NH;

  // ---- init: stage transposed bf16 weight slices (col c = u*4 + gate) ----
  for (int idx = tid; idx < NC * HID; idx += THREADS) {
    int c = idx & (NC - 1);
    int k = idx >> 5;
    int gcol = ((c & 3) << 10) + j0 + (c >> 2);
    Ut[c * U_LD + k] = f2bf(U[(size_t)k * G4 + gcol]);
  }
  for (int idx = tid; idx < NC * DIN; idx += THREADS) {
    int c = idx & (NC - 1);
    int k = idx >> 5;
    int gcol = ((c & 3) << 10) + j0 + (c >> 2);
    Wt[c * W_LD + k] = f2bf(W[(size_t)k * G4 + gcol]);
  }
  __syncthreads();

  const int l  = tid & 63;
  const int wv = tid >> 6;           // K-split 0..7
  const int cl = l & 31;             // A-row / B-col
  const int q  = l >> 5;             // k-half

  // ---- B fragments -> registers (48 VGPR) ----
  bf16x8 ubf[8], wbf[4];
  {
    const u16* ub = Ut + cl * U_LD + wv * 128 + q * 8;
#pragma unroll
    for (int s = 0; s < 8; ++s) ubf[s] = *(const bf16x8*)(ub + s * 16);
    const u16* wb = Wt + cl * W_LD + wv * 64 + q * 8;
#pragma unroll
    for (int s = 0; s < 4; ++s) wbf[s] = *(const bf16x8*)(wb + s * 16);
  }
  __syncthreads();   // staging dead; zp live from here

  // gates (tid < 256): thread -> (row pb, unit pu)
  const int pb = tid >> 3;
  const int pu = tid & 7;
  const float bi  = bias[j0 + pu];
  const float bf_ = bias[1024 + j0 + pu];
  const float bg  = bias[2048 + j0 + pu];
  const float bo  = bias[3072 + j0 + pu];
  float cA = 0.f, cB = 0.f;
  int alive = 1;

  const uint64_t hbase = (uint64_t)ws + HB_OFF;
  const uint64_t xb64  = (uint64_t)xb;
  // consumer lane base offset within a parity buffer:
  //   frag s: kblk = wv*16 + 2s + q; byte = kblk*1024 + cl*32 (+ half*16)
  const uint64_t hlane = (uint64_t)(wv * 16 + q) * 1024 + (uint64_t)cl * 32;
  // publisher leader offset: kblk=bid, row pb, unit-group (l>>2)&1
  const uint64_t puboff = (uint64_t)bid * 1024 + (uint64_t)(tid >> 3) * 32 +
                          (uint64_t)((l >> 2) & 1) * 16;

  uint32x4 hbuf[16], xr[4];

#define ISSUE_BUNDLE(NCH, NT) do {                                               \
    const uint64_t hb_ = hbase + (uint64_t)(NCH) * HB_CH +                       \
                         (uint64_t)((NT) & 1) * HB_PAR + hlane;                  \
    _Pragma("unroll")                                                            \
    for (int s_ = 0; s_ < 8; ++s_) {                                             \
      hbuf[2 * s_]     = load16_sc(hb_ + (uint64_t)s_ * 2048);                   \
      hbuf[2 * s_ + 1] = load16_sc(hb_ + (uint64_t)s_ * 2048 + 16);              \
    }                                                                            \
    const uint64_t xa_ = xb64 + (((uint64_t)(NT) * 64 + (NCH) * 32 + cl) * 512   \
                                 + (uint64_t)(wv * 64 + q * 8)) * 2;             \
    _Pragma("unroll")                                                            \
    for (int s_ = 0; s_ < 4; ++s_) xr[s_] = load16_plain(xa_ + (uint64_t)s_ * 32); \
  } while (0)

#define PHASE(CH, TT, CREG, NCH, NT) do {                                        \
    WAITV(0); SBAR();   /* drain hbuf/xr + previous publish (free ack) */        \
    const unsigned etag_ = (unsigned)(TT);                                       \
    unsigned bad_ = 0;                                                           \
    _Pragma("unroll")                                                            \
    for (int s_ = 0; s_ < 16; ++s_) {                                            \
      _Pragma("unroll")                                                          \
      for (int e_ = 0; e_ < 4; ++e_) bad_ |= (hbuf[s_][e_] ^ etag_) & 0xffffu;   \
    }                                                                            \
    if (!__all(bad_ == 0)) {   /* rare: skewed producer; bounded retry */        \
      int spins_ = 0;                                                            \
      while (alive) {                                                            \
        __builtin_amdgcn_s_sleep(2);                                             \
        const uint64_t hb_ = hbase + (uint64_t)(CH) * HB_CH +                    \
                             (uint64_t)((TT) & 1) * HB_PAR + hlane;              \
        _Pragma("unroll")                                                        \
        for (int s_ = 0; s_ < 8; ++s_) {                                         \
          hbuf[2 * s_]     = load16_sc(hb_ + (uint64_t)s_ * 2048);               \
          hbuf[2 * s_ + 1] = load16_sc(hb_ + (uint64_t)s_ * 2048 + 16);          \
        }                                                                        \
        WAITV(0); SBAR();                                                        \
        bad_ = 0;                                                                \
        _Pragma("unroll")                                                        \
        for (int s_ = 0; s_ < 16; ++s_) {                                        \
          _Pragma("unroll")                                                      \
          for (int e_ = 0; e_ < 4; ++e_) bad_ |= (hbuf[s_][e_] ^ etag_) & 0xffffu; \
        }                                                                        \
        if (__all(bad_ == 0)) break;                                             \
        if (++spins_ > (1 << 18)) { alive = 0; break; }                          \
      }                                                                          \
    }                                                                            \
    f32x16 acc = {0.f,0.f,0.f,0.f,0.f,0.f,0.f,0.f,0.f,0.f,0.f,0.f,0.f,0.f,0.f,0.f}; \
    _Pragma("unroll")                                                            \
    for (int s_ = 0; s_ < 8; ++s_) {   /* pack u32 pairs -> bf16x8, h@U */       \
      uint32x4 d0_ = hbuf[2 * s_], d1_ = hbuf[2 * s_ + 1];                       \
      uint32x4 pk_;                                                              \
      pk_[0] = (d0_[0] >> 16) | (d0_[1] & 0xffff0000u);                          \
      pk_[1] = (d0_[2] >> 16) | (d0_[3] & 0xffff0000u);                          \
      pk_[2] = (d1_[0] >> 16) | (d1_[1] & 0xffff0000u);                          \
      pk_[3] = (d1_[2] >> 16) | (d1_[3] & 0xffff0000u);                          \
      acc = __builtin_amdgcn_mfma_f32_32x32x16_bf16(                             \
          __builtin_bit_cast(bf16x8, pk_), ubf[s_], acc, 0, 0, 0);               \
    }                                                                            \
    _Pragma("unroll")                                                            \
    for (int s_ = 0; s_ < 4; ++s_)     /* x@W */                                 \
      acc = __builtin_amdgcn_mfma_f32_32x32x16_bf16(                             \
          __builtin_bit_cast(bf16x8, xr[s_]), wbf[s_], acc, 0, 0, 0);            \
    _Pragma("unroll")                                                            \
    for (int r_ = 0; r_ < 16; ++r_) {  /* C: col=cl, row=(r&3)+8*(r>>2)+4q */    \
      int rl_ = (r_ & 3) + 8 * (r_ >> 2) + 4 * q;                                \
      zp[wv][rl_][cl] = acc[r_];                                                 \
    }                                                                            \
    ISSUE_BUNDLE(NCH, NT);   /* mid-phase speculative issue for next phase */    \
    __syncthreads();   /* b1: zp write -> read */                                \
    if (tid < 256) {                                                             \
      float zi = bi, zf = bf_, zg = bg, zo = bo;                                 \
      _Pragma("unroll")                                                          \
      for (int k2 = 0; k2 < 8; ++k2) {                                           \
        float4 v = *(const float4*)&zp[k2][pb][pu * 4];                          \
        zi += v.x; zf += v.y; zg += v.z; zo += v.w;                              \
      }                                                                          \
      float ig = sigm(zi), fg = sigm(zf), og = sigm(zo);                         \
      float gg = fast_tanh(zg);                                                  \
      CREG = fg * CREG + ig * gg;                                                \
      float h = og * fast_tanh(CREG);                                            \
      unsigned hval = ((unsigned)f2bf(h) << 16) | ((unsigned)((TT) + 1) & 0xffffu); \
      int base_ = l & ~3;                                                        \
      uint32x4 hv;                                                               \
      hv[0] = __shfl(hval, base_);     hv[1] = __shfl(hval, base_ + 1);          \
      hv[2] = __shfl(hval, base_ + 2); hv[3] = __shfl(hval, base_ + 3);          \
      if ((l & 3) == 0)                                                          \
        store16_sc(hbase + (uint64_t)(CH) * HB_CH +                              \
                   (uint64_t)(((TT) + 1) & 1) * HB_PAR + puboff, hv);            \
      if ((TT) == T_STEPS - 1) {                                                 \
        float* orow = out + (size_t)((CH) * 32 + pb) * 3072 + j0 + pu;           \
        orow[0] = h; orow[1024] = h; orow[2048] = CREG;                          \
      }                                                                          \
    }                                                                            \
    __syncthreads();   /* b2: zp reads done before next phase's writes */        \
  } while (0)

  // bootstrap: bundle for phase 0 = (chain A, step 0); tag 0 = memset zeros
  ISSUE_BUNDLE(0, 0);

  for (int t = 0; t < T_STEPS; ++t) {
    const int tn = (t + 1 < T_STEPS) ? (t + 1) : (T_STEPS - 1);
    PHASE(0, t, cA, 1, t);    // next = (B, t)
    PHASE(1, t, cB, 0, tn);   // next = (A, t+1) (clamped on last iter)
  }
#undef PHASE
#undef ISSUE_BUNDLE
}

extern "C" void kernel_launch(void* const* d_in, const int* in_sizes, int n_in,
                              void* d_out, int out_size, void* d_ws, size_t ws_size,
                              hipStream_t stream) {
  const float* x = (const float*)d_in[0];
  const float* W = (const float*)d_in[1];
  const float* U = (const float*)d_in[2];
  const float* b = (const float*)d_in[3];
  float* out = (float*)d_out;

  if (ws_size < WS_NEED) return;  // loud failure: output stays poisoned

  u16* xb = (u16*)d_ws;
  // zero tagged-h buffers (tag 0 == valid h_0 = 0) — replayed every launch
  hipMemsetAsync((char*)d_ws + HB_OFF, 0, HB_BYTES, stream);
  cvt_x<<<(T_STEPS * BATCH * DIN / 8 + 255) / 256, 256, 0, stream>>>(x, xb);
  lstm_kernel<<<NBLK, THREADS, 0, stream>>>(W, U, b, xb, (char*)d_ws, out);
}